// Round 2
// baseline (192.154 us; speedup 1.0000x reference)
//
#include <hip/hip_runtime.h>
#include <math.h>

#define HIDDEN 768

// -ln(10000)/768 and -ln(10000)/256
#define K768 (-0.011992630692677323f)
#define K256 (-0.035977892078031970f)
// exp(256*K768) = 10000^(-1/3), exp(512*K768) = 10000^(-2/3)
#define C256 (0.04641588833612779f)
#define C512 (0.002154434690031884f)

typedef float nfloat4 __attribute__((ext_vector_type(4)));  // native vec for NT stores

// One row per wave, no loop: maximal TLP (occupancy-driven latency hiding),
// minimal VGPR so the allocator cannot serialize the gather burst.
__global__ __launch_bounds__(256) void emb_ln_kernel(
    const int*   __restrict__ input_ids,    // B*S
    const int*   __restrict__ tok_struct,   // B*S*3
    const int*   __restrict__ token_type,   // B*S
    const float* __restrict__ word_emb,     // VOCAB*768
    const float* __restrict__ type_emb,     // 2*768
    const float* __restrict__ ln_w,         // 768
    const float* __restrict__ ln_b,         // 768
    float*       __restrict__ out,          // B*S*768
    int S, int BS)
{
    const int lane = threadIdx.x & 63;
    const int r    = blockIdx.x * 4 + (threadIdx.x >> 6);
    if (r >= BS) return;

    // ---- indices (one serial round trip, hidden by 32 waves/CU) ----
    const int id = input_ids[r];
    const int tt = token_type[r];
    const int pp = tok_struct[3 * r];

    // ---- issue the word_emb gather immediately (dependent on id only) ----
    const float4* wrow = (const float4*)(word_emb + (size_t)id * HIDDEN);
    const float4 w0 = wrow[lane];
    const float4 w1 = wrow[lane + 64];
    const float4 w2 = wrow[lane + 128];

    // ---- independent loads: type row, ln params (L1/L2-resident) ----
    const float4* ty = (const float4*)(type_emb + tt * HIDDEN);
    const float4 t0 = ty[lane];
    const float4 t1 = ty[lane + 64];
    const float4 t2 = ty[lane + 128];
    const float4* wv = (const float4*)ln_w;
    const float4* bv = (const float4*)ln_b;
    const float4 g0 = wv[lane],       g1 = wv[lane + 64],  g2 = wv[lane + 128];
    const float4 b0 = bv[lane],       b1 = bv[lane + 64],  b2 = bv[lane + 128];

    // ---- per-lane frequency constants (VALU, overlaps the loads) ----
    const int   h0 = lane * 4;   // lane owns h = h0 + 256*j + c
    const float d0 = __expf((float)h0 * K256);
    const float d1 = __expf((float)(h0 + 2) * K256);
    const float e0 = __expf((float)h0 * K768);
    const float e2 = __expf((float)(h0 + 2) * K768);

    const float fpp = (float)pp;
    const float hs0 = __sinf(fpp * d0);
    const float hs1 = __cosf(fpp * d0);
    const float hs2 = __sinf(fpp * d1);
    const float hs3 = __cosf(fpp * d1);

    const float fs = (float)(r & (S - 1));

    float v[12];
    {
        const float4 wj[3] = {w0, w1, w2};
        const float4 tj[3] = {t0, t1, t2};
#pragma unroll
        for (int j = 0; j < 3; ++j) {
            const float scale = (j == 0) ? 1.0f : (j == 1 ? C256 : C512);
            const float a0 = fs * (e0 * scale);
            const float a1 = fs * (e2 * scale);
            v[4 * j + 0] = wj[j].x + tj[j].x + __sinf(a0) + hs0;
            v[4 * j + 1] = wj[j].y + tj[j].y + __cosf(a0) + hs1;
            v[4 * j + 2] = wj[j].z + tj[j].z + __sinf(a1) + hs2;
            v[4 * j + 3] = wj[j].w + tj[j].w + __cosf(a1) + hs3;
        }
    }

    float s1 = 0.0f, s2 = 0.0f;
#pragma unroll
    for (int k = 0; k < 12; ++k) {
        s1 += v[k];
        s2 = fmaf(v[k], v[k], s2);
    }
#pragma unroll
    for (int off = 1; off < 64; off <<= 1) {
        s1 += __shfl_xor(s1, off, 64);
        s2 += __shfl_xor(s2, off, 64);
    }

    const float inv_n = 1.0f / (float)HIDDEN;
    const float mu   = s1 * inv_n;
    const float rstd = rsqrtf(fmaxf(s2 * inv_n - mu * mu, 0.0f) + 1e-12f);

    nfloat4* orow = (nfloat4*)(out + (size_t)r * HIDDEN);
    const float4 gg[3] = {g0, g1, g2};
    const float4 bbv[3] = {b0, b1, b2};
#pragma unroll
    for (int j = 0; j < 3; ++j) {
        nfloat4 rr;
        rr.x = (v[4 * j + 0] - mu) * rstd * gg[j].x + bbv[j].x;
        rr.y = (v[4 * j + 1] - mu) * rstd * gg[j].y + bbv[j].y;
        rr.z = (v[4 * j + 2] - mu) * rstd * gg[j].z + bbv[j].z;
        rr.w = (v[4 * j + 3] - mu) * rstd * gg[j].w + bbv[j].w;
        __builtin_nontemporal_store(rr, &orow[lane + 64 * j]);
    }
}

extern "C" void kernel_launch(void* const* d_in, const int* in_sizes, int n_in,
                              void* d_out, int out_size, void* d_ws, size_t ws_size,
                              hipStream_t stream) {
    const int*   input_ids  = (const int*)  d_in[0];
    const int*   tok_struct = (const int*)  d_in[1];
    // d_in[2] = sent_struct_vec (unused by the reference output)
    const int*   token_type = (const int*)  d_in[3];
    const float* word_emb   = (const float*)d_in[4];
    const float* type_emb   = (const float*)d_in[5];
    const float* ln_w       = (const float*)d_in[6];
    const float* ln_b       = (const float*)d_in[7];
    float* out = (float*)d_out;

    const int BS = in_sizes[0];          // B * S
    const int B  = in_sizes[2] / 128;    // sent_struct_vec is B*64*2
    const int S  = BS / B;               // 4096

    // One row per wave: BS rows -> BS/4 blocks of 256 threads (8192 for BS=32768).
    int blocks = (BS + 3) / 4;
    emb_ln_kernel<<<blocks, 256, 0, stream>>>(input_ids, tok_struct, token_type,
                                              word_emb, type_emb, ln_w, ln_b,
                                              out, S, BS);
}